// Round 15
// baseline (114.427 us; speedup 1.0000x reference)
//
#include <hip/hip_runtime.h>
#include <math.h>

#define SD 10
#define MD 9

typedef short bf8 __attribute__((ext_vector_type(8)));
typedef float f32x4 __attribute__((ext_vector_type(4)));

__device__ inline ushort f2b(float f) {
    union { float f; unsigned u; } v; v.f = f;
    unsigned r = v.u + 0x7FFF + ((v.u >> 16) & 1);
    return (ushort)(r >> 16);
}

// ---------------- merged prep: small-weight pad/convert + W1f/W2f fragment-major + gh ----------------
#define WBF_TOTAL 207872
#define W5O 0
#define W6O 2048
#define W7O 4096
#define W8O 5632
#define WQO 7168
#define WSIGO 26624
#define WRO 75264
#define WSO 91648
#define WFC1O 148992
#define WFC3O 161280
#define WFC4O 182784
#define NB_WBF 812            // ceil(207872/256)
#define NB_W1F 684            // ceil(456*6*64/256)
#define NB_W2F 342            // ceil(4*57*6*64/256)
__global__ void prep_all(const float* __restrict__ w5, const float* __restrict__ w6,
                         const float* __restrict__ w7, const float* __restrict__ w8,
                         const float* __restrict__ wq, const float* __restrict__ wsig,
                         const float* __restrict__ wr, const float* __restrict__ wss,
                         const float* __restrict__ w1, const float* __restrict__ w3,
                         const float* __restrict__ w4, ushort* __restrict__ wbf,
                         const float* __restrict__ W1, ushort* __restrict__ W1f,
                         const float* __restrict__ W2, ushort* __restrict__ W2f,
                         const float* __restrict__ Q_Whh, const float* __restrict__ Q_bhh,
                         const float* __restrict__ R_Whh, const float* __restrict__ R_bhh,
                         const float* __restrict__ S_Whh, const float* __restrict__ S_bhh,
                         float* __restrict__ gh) {
    const int bid = blockIdx.x, tid = threadIdx.x;
    if (bid < NB_WBF) {
        int idx = bid * 256 + tid;
        if (idx >= WBF_TOTAL) return;
        const int offs[12] = {W5O, W6O, W7O, W8O, WQO, WSIGO, WRO, WSO, WFC1O, WFC3O, WFC4O, WBF_TOTAL};
        const int Ns[11]  = {50, 50, 45, 45, 300, 300, 243, 243, 81, 100, 100};
        const int Ks[11]  = {10, 10, 9, 9, 50, 150, 45, 207, 100, 171, 200};
        const int KPs[11] = {32, 32, 32, 32, 64, 160, 64, 224, 128, 192, 224};
        const float* srcs[11] = {w5, w6, w7, w8, wq, wsig, wr, wss, w1, w3, w4};
        int s = 0;
        for (int i = 1; i < 11; ++i) if (idx >= offs[i]) s = i;
        int loc = idx - offs[s];
        int r = loc / KPs[s], k = loc - r * KPs[s];
        float v = (r < Ns[s] && k < Ks[s]) ? srcs[s][(size_t)r * Ks[s] + k] : 0.f;
        wbf[idx] = f2b(v);
    } else if (bid < NB_WBF + NB_W1F) {
        int idx = (bid - NB_WBF) * 256 + tid;
        if (idx >= 456 * 6 * 64) return;
        int l = idx & 63, rest = idx >> 6;
        int ks = rest % 6, t = rest / 6;
        int lr = l & 15, lk = l >> 4;
        int row = t * 16 + lr;
        union { ushort u[8]; uint4 v; } o;
        #pragma unroll
        for (int j = 0; j < 8; ++j) {
            int k = ks * 32 + lk * 8 + j;
            o.u[j] = (row < 7240 && k < 181) ? f2b(W1[(size_t)row * 181 + k]) : (ushort)0;
        }
        *(uint4*)(W1f + (size_t)idx * 8) = o.v;
    } else if (bid < NB_WBF + NB_W1F + NB_W2F) {
        int idx = (bid - NB_WBF - NB_W1F) * 256 + tid;
        if (idx >= 4 * 57 * 6 * 64) return;
        int l = idx & 63, rest = idx >> 6;
        int nj = rest % 6; rest /= 6;
        int u = rest % 57, w = rest / 57;
        int lr = l & 15, lk = l >> 4;
        int row = nj * 16 + lr;
        union { ushort u8[8]; uint4 v; } o;
        #pragma unroll
        for (int j = 0; j < 8; ++j) {
            int p = w * 32 + lk * 8 + j;                 // permuted k within chunk
            int col = u * 128 + (p & 1) * 64 + (p >> 1); // inv-perm: n = (p&1)*64 + (p>>1)
            o.u8[j] = (row < 90 && col < 7240) ? f2b(W2[(size_t)row * 7240 + col]) : (ushort)0;
        }
        *(uint4*)(W2f + (size_t)idx * 8) = o.v;
    } else {
        for (int j = tid; j < 512; j += 256) {
            if (j < 300) {
                float s = Q_bhh[j];
                #pragma unroll
                for (int i = 0; i < 10; ++i) s += Q_Whh[j * 100 + 11 * i];
                gh[j] = s;
            }
            if (j < 243) {
                float s = R_bhh[j];
                #pragma unroll
                for (int i = 0; i < 9; ++i) s += R_Whh[j * 81 + 10 * i];
                gh[320 + j] = s;
                float s2 = S_bhh[j];
                #pragma unroll
                for (int i = 0; i < 9; ++i) s2 += S_Whh[j * 81 + 10 * i];
                gh[576 + j] = s2;
            }
        }
    }
}

// ---------------- generic MFMA layer ----------------
template <int KSTEPS, int MODE>
__device__ __forceinline__ void mfma_layer(
    const ushort* sX, int strideX,
    const ushort* __restrict__ Wb, int Kpad, int ntiles,
    const float* __restrict__ bias, int N,
    int w, int lr, int lk,
    float* sGi, int ldg,
    ushort* sDst, int strideD, int dcol,
    float* gDst, int gld, int row0) {
    bf8 a[KSTEPS];
    #pragma unroll
    for (int ks = 0; ks < KSTEPS; ++ks)
        a[ks] = *(const bf8*)(sX + lr * strideX + ks * 32 + lk * 8);
    for (int nt = w; nt < ntiles; nt += 4) {
        f32x4 acc = (f32x4){0.f, 0.f, 0.f, 0.f};
        #pragma unroll
        for (int ks = 0; ks < KSTEPS; ++ks) {
            bf8 Bf = *(const bf8*)(Wb + (size_t)(nt * 16 + lr) * Kpad + ks * 32 + lk * 8);
            acc = __builtin_amdgcn_mfma_f32_16x16x32_bf16(a[ks], Bf, acc, 0, 0, 0);
        }
        int n = nt * 16 + lr;
        if (n < N) {
            float b = bias[n];
            #pragma unroll
            for (int q = 0; q < 4; ++q) {
                float v = acc[q] + b;
                int m = lk * 4 + q;
                if (MODE == 0) {
                    sGi[m * ldg + n] = v;
                } else if (MODE == 1) {
                    v = fmaxf(v, 0.f);
                    sDst[m * strideD + dcol + n] = f2b(v);
                } else {
                    v = fmaxf(v, 0.f);
                    gDst[(size_t)(row0 + m) * gld + n] = v;
                }
            }
        }
    }
}

// ---------------- fused chain via MFMA; writes Xb (row-major) AND Xf (fragment-major) ----------------
#define U_NORM  0
#define U_OUT5  2176
#define U_INSIG 3328
#define U_OUT8  6016
#define U_INS   7168
#define U_HSIG  10880
#define U_TOT   13056
__global__ __launch_bounds__(256) void chain_mfma(
    const float* __restrict__ obs_diff, const float* __restrict__ obs_innov,
    const float* __restrict__ fw_evol, const float* __restrict__ fw_upd,
    const ushort* __restrict__ wbf, const float* __restrict__ gh,
    const float* __restrict__ Q_bih, const float* __restrict__ Sig_bih,
    const float* __restrict__ Sig_bhh,
    const float* __restrict__ R_bih, const float* __restrict__ S_bih,
    const float* __restrict__ fc1_b, const float* __restrict__ fc5_b,
    const float* __restrict__ fc6_b, const float* __restrict__ fc7_b,
    const float* __restrict__ fc8_b,
    float* __restrict__ o_hQ, float* __restrict__ o_hR, float* __restrict__ o_hS,
    ushort* __restrict__ Xb, ushort* __restrict__ Xf) {
    __shared__ __align__(16) ushort su[U_TOT];
    __shared__ __align__(16) float sGi[16 * 305];
    const int tid = threadIdx.x;
    const int w = tid >> 6, l = tid & 63, lr = l & 15, lk = l >> 4;
    const int row0 = blockIdx.x * 16;
    const size_t xfBase = (size_t)blockIdx.x * (6 * 64 * 8);

    for (int i = tid; i < U_TOT; i += 256) su[i] = 0;
    __syncthreads();
    if (tid < 64) {
        int v = tid >> 4, r = tid & 15;
        const float* src = (v == 0) ? fw_upd : (v == 1) ? fw_evol : (v == 2) ? obs_diff : obs_innov;
        int len = (v < 2) ? 10 : 9;
        float x[10]; float s = 0.f;
        for (int k = 0; k < len; ++k) { x[k] = src[(size_t)(row0 + r) * len + k]; s += x[k] * x[k]; }
        float sc = 1.f / fmaxf(sqrtf(s), 1e-12f);
        for (int k = 0; k < len; ++k) su[U_NORM + r * 136 + v * 32 + k] = f2b(x[k] * sc);
    }
    __syncthreads();
    mfma_layer<1, 1>(su + U_NORM + 0, 136, wbf + W5O, 32, 4, fc5_b, 50, w, lr, lk,
                     nullptr, 0, su + U_OUT5, 72, 0, nullptr, 0, 0);
    mfma_layer<1, 1>(su + U_NORM + 32, 136, wbf + W6O, 32, 4, fc6_b, 50, w, lr, lk,
                     nullptr, 0, su + U_INSIG, 168, 100, nullptr, 0, 0);
    mfma_layer<1, 1>(su + U_NORM + 64, 136, wbf + W7O, 32, 3, fc7_b, 45, w, lr, lk,
                     nullptr, 0, su + U_INS, 232, 81, nullptr, 0, 0);
    mfma_layer<1, 1>(su + U_NORM + 96, 136, wbf + W8O, 32, 3, fc8_b, 45, w, lr, lk,
                     nullptr, 0, su + U_OUT8, 72, 0, nullptr, 0, 0);
    __syncthreads();
    mfma_layer<2, 0>(su + U_OUT5, 72, wbf + WQO, 64, 19, Q_bih, 300, w, lr, lk,
                     sGi, 305, nullptr, 0, 0, nullptr, 0, 0);
    __syncthreads();
    for (int i = tid; i < 16 * 100; i += 256) {
        int r = i / 100, h = i - r * 100;
        float ir = sGi[r * 305 + h], iz = sGi[r * 305 + 100 + h], in = sGi[r * 305 + 200 + h];
        float rr = 1.f / (1.f + __expf(-(ir + gh[h])));
        float zz = 1.f / (1.f + __expf(-(iz + gh[100 + h])));
        float t = in + rr * gh[200 + h];
        float nn = 1.f - 2.f / (1.f + __expf(2.f * t));
        float h0 = ((h % 11) == 0) ? 1.f : 0.f;
        float v = (1.f - zz) * nn + zz * h0;
        su[U_INSIG + r * 168 + h] = f2b(v);
        o_hQ[(size_t)(row0 + r) * 100 + h] = v;
    }
    __syncthreads();
    mfma_layer<5, 0>(su + U_INSIG, 168, wbf + WSIGO, 160, 19, Sig_bih, 300, w, lr, lk,
                     sGi, 305, nullptr, 0, 0, nullptr, 0, 0);
    __syncthreads();
    for (int i = tid; i < 16 * 100; i += 256) {
        int r = i / 100, h = i - r * 100;
        float ir = sGi[r * 305 + h], iz = sGi[r * 305 + 100 + h], in = sGi[r * 305 + 200 + h];
        float rr = 1.f / (1.f + __expf(-(ir + Sig_bhh[h])));
        float zz = 1.f / (1.f + __expf(-(iz + Sig_bhh[100 + h])));
        float t = in + rr * Sig_bhh[200 + h];
        float nn = 1.f - 2.f / (1.f + __expf(2.f * t));
        float v = (1.f - zz) * nn;
        ushort bv = f2b(v);
        su[U_HSIG + r * 136 + h] = bv;
        Xb[(size_t)(row0 + r) * 192 + h] = bv;
        int ks = h >> 5, lkx = (h >> 3) & 3, j = h & 7;
        Xf[xfBase + (((size_t)ks * 64) + lkx * 16 + r) * 8 + j] = bv;
    }
    __syncthreads();
    mfma_layer<4, 1>(su + U_HSIG, 136, wbf + WFC1O, 128, 6, fc1_b, 81, w, lr, lk,
                     nullptr, 0, su + U_INS, 232, 0, nullptr, 0, 0);
    mfma_layer<2, 0>(su + U_OUT8, 72, wbf + WRO, 64, 16, R_bih, 243, w, lr, lk,
                     sGi, 305, nullptr, 0, 0, nullptr, 0, 0);
    __syncthreads();
    for (int i = tid; i < 16 * 81; i += 256) {
        int r = i / 81, h = i - r * 81;
        float ir = sGi[r * 305 + h], iz = sGi[r * 305 + 81 + h], in = sGi[r * 305 + 162 + h];
        float rr = 1.f / (1.f + __expf(-(ir + gh[320 + h])));
        float zz = 1.f / (1.f + __expf(-(iz + gh[320 + 81 + h])));
        float t = in + rr * gh[320 + 162 + h];
        float nn = 1.f - 2.f / (1.f + __expf(2.f * t));
        float h0 = ((h % 10) == 0) ? 1.f : 0.f;
        float v = (1.f - zz) * nn + zz * h0;
        su[U_INS + r * 232 + 126 + h] = f2b(v);
        o_hR[(size_t)(row0 + r) * 81 + h] = v;
    }
    __syncthreads();
    mfma_layer<7, 0>(su + U_INS, 232, wbf + WSO, 224, 16, S_bih, 243, w, lr, lk,
                     sGi, 305, nullptr, 0, 0, nullptr, 0, 0);
    __syncthreads();
    for (int i = tid; i < 16 * 81; i += 256) {
        int r = i / 81, h = i - r * 81;
        float ir = sGi[r * 305 + h], iz = sGi[r * 305 + 81 + h], in = sGi[r * 305 + 162 + h];
        float rr = 1.f / (1.f + __expf(-(ir + gh[576 + h])));
        float zz = 1.f / (1.f + __expf(-(iz + gh[576 + 81 + h])));
        float t = in + rr * gh[576 + 162 + h];
        float nn = 1.f - 2.f / (1.f + __expf(2.f * t));
        float h0 = ((h % 10) == 0) ? 1.f : 0.f;
        float v = (1.f - zz) * nn + zz * h0;
        o_hS[(size_t)(row0 + r) * 81 + h] = v;
        ushort bv = f2b(v);
        Xb[(size_t)(row0 + r) * 192 + 100 + h] = bv;
        int c = 100 + h;
        int ks = c >> 5, lkx = (c >> 3) & 3, j = c & 7;
        Xf[xfBase + (((size_t)ks * 64) + lkx * 16 + r) * 8 + j] = bv;
    }
}

// ---------------- FC2 MFMA v8: ks-outer GEMM1 (no spill), A-read-once, packed b32 hid ----------------
// grid 512 = 128 mt x 4 split; wave w: GEMM1 W1-tiles (u*8+{0,4}+w), GEMM2 K-strip w (permuted k).
#define NSPLIT 4
#define HIDP 72   // hid LDS stride in elements: 144 B = 16B-aligned, <=2-way banks
__global__ __launch_bounds__(256, 2) void fc2_mfma(
    const ushort* __restrict__ Xf, const ushort* __restrict__ W1f,
    const float* __restrict__ b1, const ushort* __restrict__ W2f,
    float* __restrict__ partial, int B) {
    __shared__ ushort sX[4 * 6 * 64 * 8];     // 24576 B (aliased as red1 at end)
    __shared__ ushort sHid[4][64 * HIDP];     // 36864 B (aliased as red2 at end)
    const int tid = threadIdx.x;
    const int w = tid >> 6, l = tid & 63;
    const int lr = l & 15, lk = l >> 4;
    const int mt = blockIdx.x >> 2, split = blockIdx.x & 3;
    const int m0 = mt * 64;
    const int u0 = (57 * split) / NSPLIT, u1 = (57 * (split + 1)) / NSPLIT;

    // stage X tile (linear fragment-major) via global_load_lds: 24KB
    {
        const ushort* src = Xf + (size_t)mt * (4 * 6 * 64 * 8);
        #pragma unroll
        for (int p = 0; p < 6; ++p) {
            __builtin_amdgcn_global_load_lds(
                (const __attribute__((address_space(1))) unsigned int*)(src + (p * 256 + tid) * 8),
                (__attribute__((address_space(3))) unsigned int*)(sX + (p * 256 + tid) * 8),
                16, 0, 0);
        }
        asm volatile("s_waitcnt vmcnt(0)" ::: "memory");
        __syncthreads();
    }

    f32x4 acc2[4][6];
    #pragma unroll
    for (int mi = 0; mi < 4; ++mi)
        #pragma unroll
        for (int nj = 0; nj < 6; ++nj) acc2[mi][nj] = (f32x4){0.f, 0.f, 0.f, 0.f};

    ushort* myHid = &sHid[w][0];

    for (int u = u0; u < u1; ++u) {
        const int gn0 = u * 128 + w * 16 + lr;
        const int gn1 = gn0 + 64;
        const float bias0 = (gn0 < 7240) ? b1[gn0] : 0.f;
        const float bias1 = (gn1 < 7240) ? b1[gn1] : 0.f;
        const size_t t0 = ((size_t)(u * 8 + w)) * 6;        // h=0 tile
        const size_t t1 = ((size_t)(u * 8 + 4 + w)) * 6;    // h=1 tile
        // GEMM1, ks-outer: only one B-pair live at a time (16 regs) -> no spill;
        // each A-frag read once feeds both halves.
        f32x4 a0[4], a1[4];
        #pragma unroll
        for (int mi = 0; mi < 4; ++mi) { a0[mi] = (f32x4){0.f,0.f,0.f,0.f}; a1[mi] = (f32x4){0.f,0.f,0.f,0.f}; }
        #pragma unroll
        for (int ks = 0; ks < 6; ++ks) {
            bf8 B0 = *(const bf8*)(W1f + ((t0 + ks) * 64 + l) * 8);
            bf8 B1 = *(const bf8*)(W1f + ((t1 + ks) * 64 + l) * 8);
            #pragma unroll
            for (int mi = 0; mi < 4; ++mi) {
                bf8 Af = *(const bf8*)(sX + ((mi * 6 + ks) * 64 + l) * 8);
                a0[mi] = __builtin_amdgcn_mfma_f32_16x16x32_bf16(Af, B0, a0[mi], 0, 0, 0);
                a1[mi] = __builtin_amdgcn_mfma_f32_16x16x32_bf16(Af, B1, a1[mi], 0, 0, 0);
            }
        }
        // packed b32 hid writes: (h0,h1) pair at local k-cols 2lr, 2lr+1
        #pragma unroll
        for (int mi = 0; mi < 4; ++mi)
            #pragma unroll
            for (int q = 0; q < 4; ++q) {
                int m = mi * 16 + lk * 4 + q;
                unsigned pv = (unsigned)f2b(fmaxf(a0[mi][q] + bias0, 0.f))
                            | ((unsigned)f2b(fmaxf(a1[mi][q] + bias1, 0.f)) << 16);
                *(unsigned*)(myHid + m * HIDP + 2 * lr) = pv;
            }
        // GEMM2 on the wave's 32-k strip (permuted k matches W2f prep); wave-private LDS, in-order
        bf8 Wf2[6];
        const size_t w2base = ((size_t)w * 57 + u) * 6;
        #pragma unroll
        for (int nj = 0; nj < 6; ++nj)
            Wf2[nj] = *(const bf8*)(W2f + ((w2base + nj) * 64 + l) * 8);
        bf8 aF[4];
        #pragma unroll
        for (int mi = 0; mi < 4; ++mi)
            aF[mi] = *(const bf8*)(myHid + (mi * 16 + lr) * HIDP + lk * 8);
        #pragma unroll
        for (int nj = 0; nj < 6; ++nj)
            #pragma unroll
            for (int mi = 0; mi < 4; ++mi)
                acc2[mi][nj] = __builtin_amdgcn_mfma_f32_16x16x32_bf16(aF[mi], Wf2[nj], acc2[mi][nj], 0, 0, 0);
    }

    // cross-wave K-strip reduction (sX/sHid no longer needed -> alias)
    float* red1 = (float*)sX;
    float* red2 = (float*)&sHid[0][0];
    __syncthreads();
    if (w == 1 || w == 3) {
        float* r_ = (w == 1) ? red1 : red2;
        #pragma unroll
        for (int mi = 0; mi < 4; ++mi)
            #pragma unroll
            for (int nj = 0; nj < 6; ++nj)
                #pragma unroll
                for (int q = 0; q < 4; ++q)
                    r_[(mi * 16 + lk * 4 + q) * 96 + nj * 16 + lr] = acc2[mi][nj][q];
    }
    __syncthreads();
    if (w == 0 || w == 2) {
        float* r_ = (w == 0) ? red1 : red2;
        #pragma unroll
        for (int mi = 0; mi < 4; ++mi)
            #pragma unroll
            for (int nj = 0; nj < 6; ++nj)
                #pragma unroll
                for (int q = 0; q < 4; ++q)
                    r_[(mi * 16 + lk * 4 + q) * 96 + nj * 16 + lr] += acc2[mi][nj][q];
    }
    __syncthreads();
    float* dst = partial + ((size_t)split * B + m0) * 96;
    for (int i = tid; i < 64 * 96; i += 256) dst[i] = red1[i] + red2[i];
}

// ---------------- fused tail: combine 4 partials + FC3 + FC4 via MFMA ----------------
__global__ __launch_bounds__(256) void tail_mfma(
    const float* __restrict__ partial, const float* __restrict__ b2,
    const ushort* __restrict__ Xb,
    const ushort* __restrict__ wbf, const float* __restrict__ fc3_b,
    const float* __restrict__ fc4_b,
    float* __restrict__ o_kg, float* __restrict__ o_hSn, int B) {
    __shared__ __align__(16) ushort s3[16 * 200];
    __shared__ __align__(16) ushort s4[16 * 232];
    const int tid = threadIdx.x;
    const int w = tid >> 6, l = tid & 63, lr = l & 15, lk = l >> 4;
    const int row0 = blockIdx.x * 16;

    for (int i = tid; i < 16 * 200; i += 256) s3[i] = 0;
    for (int i = tid; i < 16 * 232; i += 256) s4[i] = 0;
    __syncthreads();
    for (int i = tid; i < 16 * 81; i += 256) {
        int r = i / 81, n = i - r * 81;
        s3[r * 200 + n] = Xb[(size_t)(row0 + r) * 192 + 100 + n];
    }
    for (int i = tid; i < 16 * 100; i += 256) {
        int r = i / 100, n = i - r * 100;
        s4[r * 232 + n] = Xb[(size_t)(row0 + r) * 192 + n];
    }
    for (int i = tid; i < 16 * 90; i += 256) {
        int r = i / 90, n = i - r * 90;
        size_t rw = (size_t)(row0 + r);
        float v = b2[n];
        #pragma unroll
        for (int s = 0; s < NSPLIT; ++s) v += partial[((size_t)s * B + rw) * 96 + n];
        o_kg[rw * 90 + n] = v;
        s3[r * 200 + 81 + n] = f2b(v);
    }
    __syncthreads();
    mfma_layer<6, 1>(s3, 200, wbf + WFC3O, 192, 7, fc3_b, 100, w, lr, lk,
                     nullptr, 0, s4, 232, 100, nullptr, 0, 0);
    __syncthreads();
    mfma_layer<7, 2>(s4, 232, wbf + WFC4O, 224, 7, fc4_b, 100, w, lr, lk,
                     nullptr, 0, nullptr, 0, 0, o_hSn, 100, row0);
}

extern "C" void kernel_launch(void* const* d_in, const int* in_sizes, int n_in,
                              void* d_out, int out_size, void* d_ws, size_t ws_size,
                              hipStream_t stream) {
    const float* obs_diff  = (const float*)d_in[0];
    const float* obs_innov = (const float*)d_in[1];
    const float* fw_evol   = (const float*)d_in[2];
    const float* fw_upd    = (const float*)d_in[3];
    const float* Q_Wih  = (const float*)d_in[4];
    const float* Q_Whh  = (const float*)d_in[5];
    const float* Q_bih  = (const float*)d_in[6];
    const float* Q_bhh  = (const float*)d_in[7];
    const float* Sig_Wih = (const float*)d_in[8];
    const float* Sig_bih = (const float*)d_in[10];
    const float* Sig_bhh = (const float*)d_in[11];
    const float* S_Wih  = (const float*)d_in[12];
    const float* S_Whh  = (const float*)d_in[13];
    const float* S_bih  = (const float*)d_in[14];
    const float* S_bhh  = (const float*)d_in[15];
    const float* R_Wih  = (const float*)d_in[16];
    const float* R_Whh  = (const float*)d_in[17];
    const float* R_bih  = (const float*)d_in[18];
    const float* R_bhh  = (const float*)d_in[19];
    const float* fc1_W = (const float*)d_in[20];
    const float* fc1_b = (const float*)d_in[21];
    const float* fc2_W1 = (const float*)d_in[22];
    const float* fc2_b1 = (const float*)d_in[23];
    const float* fc2_W2 = (const float*)d_in[24];
    const float* fc2_b2 = (const float*)d_in[25];
    const float* fc3_W = (const float*)d_in[26];
    const float* fc3_b = (const float*)d_in[27];
    const float* fc4_W = (const float*)d_in[28];
    const float* fc4_b = (const float*)d_in[29];
    const float* fc5_W = (const float*)d_in[30];
    const float* fc5_b = (const float*)d_in[31];
    const float* fc6_W = (const float*)d_in[32];
    const float* fc6_b = (const float*)d_in[33];
    const float* fc7_W = (const float*)d_in[34];
    const float* fc7_b = (const float*)d_in[35];
    const float* fc8_W = (const float*)d_in[36];
    const float* fc8_b = (const float*)d_in[37];

    const int B = in_sizes[0] / MD;   // 8192
    float* ws = (float*)d_ws;
    float* gh = ws;
    size_t off = 1024;
    ushort* wbf = (ushort*)(ws + off); off += WBF_TOTAL / 2;
    ushort* Xb  = (ushort*)(ws + off); off += (size_t)B * 96;      // [B][192] bf16
    ushort* Xf  = (ushort*)(ws + off); off += (size_t)B * 96;      // fragment-major X
    ushort* W1f = (ushort*)(ws + off); off += 456 * 6 * 64 * 8 / 2;
    ushort* W2f = (ushort*)(ws + off); off += 4 * 57 * 6 * 64 * 8 / 2;
    float* part = ws + off; off += (size_t)NSPLIT * B * 96;

    float* out = (float*)d_out;
    float* o_kg  = out;
    float* o_hS  = out + (size_t)B * 90;
    float* o_hSn = out + (size_t)B * 171;
    float* o_hQ  = out + (size_t)B * 271;
    float* o_hR  = out + (size_t)B * 371;

    hipLaunchKernelGGL(prep_all, dim3(NB_WBF + NB_W1F + NB_W2F + 1), dim3(256), 0, stream,
                       fc5_W, fc6_W, fc7_W, fc8_W, Q_Wih, Sig_Wih, R_Wih, S_Wih,
                       fc1_W, fc3_W, fc4_W, wbf,
                       fc2_W1, W1f, fc2_W2, W2f,
                       Q_Whh, Q_bhh, R_Whh, R_bhh, S_Whh, S_bhh, gh);
    hipLaunchKernelGGL(chain_mfma, dim3(B / 16), dim3(256), 0, stream,
                       obs_diff, obs_innov, fw_evol, fw_upd,
                       wbf, gh, Q_bih, Sig_bih, Sig_bhh, R_bih, S_bih,
                       fc1_b, fc5_b, fc6_b, fc7_b, fc8_b,
                       o_hQ, o_hR, o_hS, Xb, Xf);
    hipLaunchKernelGGL(fc2_mfma, dim3(128 * NSPLIT), dim3(256), 0, stream,
                       Xf, W1f, fc2_b1, W2f, part, B);
    hipLaunchKernelGGL(tail_mfma, dim3(B / 16), dim3(256), 0, stream,
                       part, fc2_b2, Xb, wbf, fc3_b, fc4_b,
                       o_kg, o_hSn, B);
}

// Round 16
// 108.543 us; speedup vs baseline: 1.0542x; 1.0542x over previous
//
#include <hip/hip_runtime.h>
#include <math.h>

#define SD 10
#define MD 9

typedef short bf8 __attribute__((ext_vector_type(8)));
typedef float f32x4 __attribute__((ext_vector_type(4)));

__device__ inline ushort f2b(float f) {
    union { float f; unsigned u; } v; v.f = f;
    unsigned r = v.u + 0x7FFF + ((v.u >> 16) & 1);
    return (ushort)(r >> 16);
}

// ---------------- merged prep: small-weight pad/convert + W1f/W2f fragment-major + gh ----------------
#define WBF_TOTAL 207872
#define W5O 0
#define W6O 2048
#define W7O 4096
#define W8O 5632
#define WQO 7168
#define WSIGO 26624
#define WRO 75264
#define WSO 91648
#define WFC1O 148992
#define WFC3O 161280
#define WFC4O 182784
#define NB_WBF 812            // ceil(207872/256)
#define NB_W1F 684            // ceil(456*6*64/256)
#define NB_W2F 342            // ceil(4*57*6*64/256)
__global__ void prep_all(const float* __restrict__ w5, const float* __restrict__ w6,
                         const float* __restrict__ w7, const float* __restrict__ w8,
                         const float* __restrict__ wq, const float* __restrict__ wsig,
                         const float* __restrict__ wr, const float* __restrict__ wss,
                         const float* __restrict__ w1, const float* __restrict__ w3,
                         const float* __restrict__ w4, ushort* __restrict__ wbf,
                         const float* __restrict__ W1, ushort* __restrict__ W1f,
                         const float* __restrict__ W2, ushort* __restrict__ W2f,
                         const float* __restrict__ Q_Whh, const float* __restrict__ Q_bhh,
                         const float* __restrict__ R_Whh, const float* __restrict__ R_bhh,
                         const float* __restrict__ S_Whh, const float* __restrict__ S_bhh,
                         float* __restrict__ gh) {
    const int bid = blockIdx.x, tid = threadIdx.x;
    if (bid < NB_WBF) {
        int idx = bid * 256 + tid;
        if (idx >= WBF_TOTAL) return;
        const int offs[12] = {W5O, W6O, W7O, W8O, WQO, WSIGO, WRO, WSO, WFC1O, WFC3O, WFC4O, WBF_TOTAL};
        const int Ns[11]  = {50, 50, 45, 45, 300, 300, 243, 243, 81, 100, 100};
        const int Ks[11]  = {10, 10, 9, 9, 50, 150, 45, 207, 100, 171, 200};
        const int KPs[11] = {32, 32, 32, 32, 64, 160, 64, 224, 128, 192, 224};
        const float* srcs[11] = {w5, w6, w7, w8, wq, wsig, wr, wss, w1, w3, w4};
        int s = 0;
        for (int i = 1; i < 11; ++i) if (idx >= offs[i]) s = i;
        int loc = idx - offs[s];
        int r = loc / KPs[s], k = loc - r * KPs[s];
        float v = (r < Ns[s] && k < Ks[s]) ? srcs[s][(size_t)r * Ks[s] + k] : 0.f;
        wbf[idx] = f2b(v);
    } else if (bid < NB_WBF + NB_W1F) {
        int idx = (bid - NB_WBF) * 256 + tid;
        if (idx >= 456 * 6 * 64) return;
        int l = idx & 63, rest = idx >> 6;
        int ks = rest % 6, t = rest / 6;
        int lr = l & 15, lk = l >> 4;
        int row = t * 16 + lr;
        union { ushort u[8]; uint4 v; } o;
        #pragma unroll
        for (int j = 0; j < 8; ++j) {
            int k = ks * 32 + lk * 8 + j;
            o.u[j] = (row < 7240 && k < 181) ? f2b(W1[(size_t)row * 181 + k]) : (ushort)0;
        }
        *(uint4*)(W1f + (size_t)idx * 8) = o.v;
    } else if (bid < NB_WBF + NB_W1F + NB_W2F) {
        int idx = (bid - NB_WBF - NB_W1F) * 256 + tid;
        if (idx >= 4 * 57 * 6 * 64) return;
        int l = idx & 63, rest = idx >> 6;
        int nj = rest % 6; rest /= 6;
        int u = rest % 57, w = rest / 57;
        int lr = l & 15, lk = l >> 4;
        int row = nj * 16 + lr;
        union { ushort u8[8]; uint4 v; } o;
        #pragma unroll
        for (int j = 0; j < 8; ++j) {
            int p = w * 32 + lk * 8 + j;                 // permuted k within chunk
            int col = u * 128 + (p & 1) * 64 + (p >> 1); // inv-perm: n = (p&1)*64 + (p>>1)
            o.u8[j] = (row < 90 && col < 7240) ? f2b(W2[(size_t)row * 7240 + col]) : (ushort)0;
        }
        *(uint4*)(W2f + (size_t)idx * 8) = o.v;
    } else {
        for (int j = tid; j < 512; j += 256) {
            if (j < 300) {
                float s = Q_bhh[j];
                #pragma unroll
                for (int i = 0; i < 10; ++i) s += Q_Whh[j * 100 + 11 * i];
                gh[j] = s;
            }
            if (j < 243) {
                float s = R_bhh[j];
                #pragma unroll
                for (int i = 0; i < 9; ++i) s += R_Whh[j * 81 + 10 * i];
                gh[320 + j] = s;
                float s2 = S_bhh[j];
                #pragma unroll
                for (int i = 0; i < 9; ++i) s2 += S_Whh[j * 81 + 10 * i];
                gh[576 + j] = s2;
            }
        }
    }
}

// ---------------- generic MFMA layer ----------------
template <int KSTEPS, int MODE>
__device__ __forceinline__ void mfma_layer(
    const ushort* sX, int strideX,
    const ushort* __restrict__ Wb, int Kpad, int ntiles,
    const float* __restrict__ bias, int N,
    int w, int lr, int lk,
    float* sGi, int ldg,
    ushort* sDst, int strideD, int dcol,
    float* gDst, int gld, int row0) {
    bf8 a[KSTEPS];
    #pragma unroll
    for (int ks = 0; ks < KSTEPS; ++ks)
        a[ks] = *(const bf8*)(sX + lr * strideX + ks * 32 + lk * 8);
    for (int nt = w; nt < ntiles; nt += 4) {
        f32x4 acc = (f32x4){0.f, 0.f, 0.f, 0.f};
        #pragma unroll
        for (int ks = 0; ks < KSTEPS; ++ks) {
            bf8 Bf = *(const bf8*)(Wb + (size_t)(nt * 16 + lr) * Kpad + ks * 32 + lk * 8);
            acc = __builtin_amdgcn_mfma_f32_16x16x32_bf16(a[ks], Bf, acc, 0, 0, 0);
        }
        int n = nt * 16 + lr;
        if (n < N) {
            float b = bias[n];
            #pragma unroll
            for (int q = 0; q < 4; ++q) {
                float v = acc[q] + b;
                int m = lk * 4 + q;
                if (MODE == 0) {
                    sGi[m * ldg + n] = v;
                } else if (MODE == 1) {
                    v = fmaxf(v, 0.f);
                    sDst[m * strideD + dcol + n] = f2b(v);
                } else {
                    v = fmaxf(v, 0.f);
                    gDst[(size_t)(row0 + m) * gld + n] = v;
                }
            }
        }
    }
}

// ---------------- fused chain via MFMA; writes Xb (row-major) AND Xf (fragment-major) ----------------
#define U_NORM  0
#define U_OUT5  2176
#define U_INSIG 3328
#define U_OUT8  6016
#define U_INS   7168
#define U_HSIG  10880
#define U_TOT   13056
__global__ __launch_bounds__(256) void chain_mfma(
    const float* __restrict__ obs_diff, const float* __restrict__ obs_innov,
    const float* __restrict__ fw_evol, const float* __restrict__ fw_upd,
    const ushort* __restrict__ wbf, const float* __restrict__ gh,
    const float* __restrict__ Q_bih, const float* __restrict__ Sig_bih,
    const float* __restrict__ Sig_bhh,
    const float* __restrict__ R_bih, const float* __restrict__ S_bih,
    const float* __restrict__ fc1_b, const float* __restrict__ fc5_b,
    const float* __restrict__ fc6_b, const float* __restrict__ fc7_b,
    const float* __restrict__ fc8_b,
    float* __restrict__ o_hQ, float* __restrict__ o_hR, float* __restrict__ o_hS,
    ushort* __restrict__ Xb, ushort* __restrict__ Xf) {
    __shared__ __align__(16) ushort su[U_TOT];
    __shared__ __align__(16) float sGi[16 * 305];
    const int tid = threadIdx.x;
    const int w = tid >> 6, l = tid & 63, lr = l & 15, lk = l >> 4;
    const int row0 = blockIdx.x * 16;
    const size_t xfBase = (size_t)blockIdx.x * (6 * 64 * 8);

    for (int i = tid; i < U_TOT; i += 256) su[i] = 0;
    __syncthreads();
    if (tid < 64) {
        int v = tid >> 4, r = tid & 15;
        const float* src = (v == 0) ? fw_upd : (v == 1) ? fw_evol : (v == 2) ? obs_diff : obs_innov;
        int len = (v < 2) ? 10 : 9;
        float x[10]; float s = 0.f;
        for (int k = 0; k < len; ++k) { x[k] = src[(size_t)(row0 + r) * len + k]; s += x[k] * x[k]; }
        float sc = 1.f / fmaxf(sqrtf(s), 1e-12f);
        for (int k = 0; k < len; ++k) su[U_NORM + r * 136 + v * 32 + k] = f2b(x[k] * sc);
    }
    __syncthreads();
    mfma_layer<1, 1>(su + U_NORM + 0, 136, wbf + W5O, 32, 4, fc5_b, 50, w, lr, lk,
                     nullptr, 0, su + U_OUT5, 72, 0, nullptr, 0, 0);
    mfma_layer<1, 1>(su + U_NORM + 32, 136, wbf + W6O, 32, 4, fc6_b, 50, w, lr, lk,
                     nullptr, 0, su + U_INSIG, 168, 100, nullptr, 0, 0);
    mfma_layer<1, 1>(su + U_NORM + 64, 136, wbf + W7O, 32, 3, fc7_b, 45, w, lr, lk,
                     nullptr, 0, su + U_INS, 232, 81, nullptr, 0, 0);
    mfma_layer<1, 1>(su + U_NORM + 96, 136, wbf + W8O, 32, 3, fc8_b, 45, w, lr, lk,
                     nullptr, 0, su + U_OUT8, 72, 0, nullptr, 0, 0);
    __syncthreads();
    mfma_layer<2, 0>(su + U_OUT5, 72, wbf + WQO, 64, 19, Q_bih, 300, w, lr, lk,
                     sGi, 305, nullptr, 0, 0, nullptr, 0, 0);
    __syncthreads();
    for (int i = tid; i < 16 * 100; i += 256) {
        int r = i / 100, h = i - r * 100;
        float ir = sGi[r * 305 + h], iz = sGi[r * 305 + 100 + h], in = sGi[r * 305 + 200 + h];
        float rr = 1.f / (1.f + __expf(-(ir + gh[h])));
        float zz = 1.f / (1.f + __expf(-(iz + gh[100 + h])));
        float t = in + rr * gh[200 + h];
        float nn = 1.f - 2.f / (1.f + __expf(2.f * t));
        float h0 = ((h % 11) == 0) ? 1.f : 0.f;
        float v = (1.f - zz) * nn + zz * h0;
        su[U_INSIG + r * 168 + h] = f2b(v);
        o_hQ[(size_t)(row0 + r) * 100 + h] = v;
    }
    __syncthreads();
    mfma_layer<5, 0>(su + U_INSIG, 168, wbf + WSIGO, 160, 19, Sig_bih, 300, w, lr, lk,
                     sGi, 305, nullptr, 0, 0, nullptr, 0, 0);
    __syncthreads();
    for (int i = tid; i < 16 * 100; i += 256) {
        int r = i / 100, h = i - r * 100;
        float ir = sGi[r * 305 + h], iz = sGi[r * 305 + 100 + h], in = sGi[r * 305 + 200 + h];
        float rr = 1.f / (1.f + __expf(-(ir + Sig_bhh[h])));
        float zz = 1.f / (1.f + __expf(-(iz + Sig_bhh[100 + h])));
        float t = in + rr * Sig_bhh[200 + h];
        float nn = 1.f - 2.f / (1.f + __expf(2.f * t));
        float v = (1.f - zz) * nn;
        ushort bv = f2b(v);
        su[U_HSIG + r * 136 + h] = bv;
        Xb[(size_t)(row0 + r) * 192 + h] = bv;
        int ks = h >> 5, lkx = (h >> 3) & 3, j = h & 7;
        Xf[xfBase + (((size_t)ks * 64) + lkx * 16 + r) * 8 + j] = bv;
    }
    __syncthreads();
    mfma_layer<4, 1>(su + U_HSIG, 136, wbf + WFC1O, 128, 6, fc1_b, 81, w, lr, lk,
                     nullptr, 0, su + U_INS, 232, 0, nullptr, 0, 0);
    mfma_layer<2, 0>(su + U_OUT8, 72, wbf + WRO, 64, 16, R_bih, 243, w, lr, lk,
                     sGi, 305, nullptr, 0, 0, nullptr, 0, 0);
    __syncthreads();
    for (int i = tid; i < 16 * 81; i += 256) {
        int r = i / 81, h = i - r * 81;
        float ir = sGi[r * 305 + h], iz = sGi[r * 305 + 81 + h], in = sGi[r * 305 + 162 + h];
        float rr = 1.f / (1.f + __expf(-(ir + gh[320 + h])));
        float zz = 1.f / (1.f + __expf(-(iz + gh[320 + 81 + h])));
        float t = in + rr * gh[320 + 162 + h];
        float nn = 1.f - 2.f / (1.f + __expf(2.f * t));
        float h0 = ((h % 10) == 0) ? 1.f : 0.f;
        float v = (1.f - zz) * nn + zz * h0;
        su[U_INS + r * 232 + 126 + h] = f2b(v);
        o_hR[(size_t)(row0 + r) * 81 + h] = v;
    }
    __syncthreads();
    mfma_layer<7, 0>(su + U_INS, 232, wbf + WSO, 224, 16, S_bih, 243, w, lr, lk,
                     sGi, 305, nullptr, 0, 0, nullptr, 0, 0);
    __syncthreads();
    for (int i = tid; i < 16 * 81; i += 256) {
        int r = i / 81, h = i - r * 81;
        float ir = sGi[r * 305 + h], iz = sGi[r * 305 + 81 + h], in = sGi[r * 305 + 162 + h];
        float rr = 1.f / (1.f + __expf(-(ir + gh[576 + h])));
        float zz = 1.f / (1.f + __expf(-(iz + gh[576 + 81 + h])));
        float t = in + rr * gh[576 + 162 + h];
        float nn = 1.f - 2.f / (1.f + __expf(2.f * t));
        float h0 = ((h % 10) == 0) ? 1.f : 0.f;
        float v = (1.f - zz) * nn + zz * h0;
        o_hS[(size_t)(row0 + r) * 81 + h] = v;
        ushort bv = f2b(v);
        Xb[(size_t)(row0 + r) * 192 + 100 + h] = bv;
        int c = 100 + h;
        int ks = c >> 5, lkx = (c >> 3) & 3, j = c & 7;
        Xf[xfBase + (((size_t)ks * 64) + lkx * 16 + r) * 8 + j] = bv;
    }
}

// ---------------- FC2 MFMA v7 (r14 best): A-in-LDS, mi-outer batched B-frags, packed b32 hid ----------------
// grid 512 = 128 mt x 4 split; wave w: GEMM1 W1-tiles (u*8+{0,4}+w), GEMM2 K-strip w (permuted k).
#define NSPLIT 4
#define HIDP 72   // hid LDS stride in elements: 144 B = 16B-aligned, <=2-way banks
__global__ __launch_bounds__(256, 2) void fc2_mfma(
    const ushort* __restrict__ Xf, const ushort* __restrict__ W1f,
    const float* __restrict__ b1, const ushort* __restrict__ W2f,
    float* __restrict__ partial, int B) {
    __shared__ ushort sX[4 * 6 * 64 * 8];     // 24576 B (aliased as red1 at end)
    __shared__ ushort sHid[4][64 * HIDP];     // 36864 B (aliased as red2 at end)
    const int tid = threadIdx.x;
    const int w = tid >> 6, l = tid & 63;
    const int lr = l & 15, lk = l >> 4;
    const int mt = blockIdx.x >> 2, split = blockIdx.x & 3;
    const int m0 = mt * 64;
    const int u0 = (57 * split) / NSPLIT, u1 = (57 * (split + 1)) / NSPLIT;

    // stage X tile (linear fragment-major) via global_load_lds: 24KB
    {
        const ushort* src = Xf + (size_t)mt * (4 * 6 * 64 * 8);
        #pragma unroll
        for (int p = 0; p < 6; ++p) {
            __builtin_amdgcn_global_load_lds(
                (const __attribute__((address_space(1))) unsigned int*)(src + (p * 256 + tid) * 8),
                (__attribute__((address_space(3))) unsigned int*)(sX + (p * 256 + tid) * 8),
                16, 0, 0);
        }
        asm volatile("s_waitcnt vmcnt(0)" ::: "memory");
        __syncthreads();
    }

    f32x4 acc2[4][6];
    #pragma unroll
    for (int mi = 0; mi < 4; ++mi)
        #pragma unroll
        for (int nj = 0; nj < 6; ++nj) acc2[mi][nj] = (f32x4){0.f, 0.f, 0.f, 0.f};

    ushort* myHid = &sHid[w][0];

    for (int u = u0; u < u1; ++u) {
        // batch both halves' W1 fragments (coalesced 1KB loads, one latency exposure)
        bf8 B0[6], B1[6];
        const size_t t0 = ((size_t)(u * 8 + w)) * 6;
        const size_t t1 = ((size_t)(u * 8 + 4 + w)) * 6;
        #pragma unroll
        for (int ks = 0; ks < 6; ++ks) {
            B0[ks] = *(const bf8*)(W1f + ((t0 + ks) * 64 + l) * 8);
            B1[ks] = *(const bf8*)(W1f + ((t1 + ks) * 64 + l) * 8);
        }
        const int gn0 = u * 128 + w * 16 + lr;
        const int gn1 = gn0 + 64;
        const float bias0 = (gn0 < 7240) ? b1[gn0] : 0.f;
        const float bias1 = (gn1 < 7240) ? b1[gn1] : 0.f;
        // GEMM1: each A-frag read ONCE, feeds both halves; hid written as packed b32 (h0|h1)
        #pragma unroll
        for (int mi = 0; mi < 4; ++mi) {
            f32x4 a0 = (f32x4){0.f, 0.f, 0.f, 0.f};
            f32x4 a1 = (f32x4){0.f, 0.f, 0.f, 0.f};
            #pragma unroll
            for (int ks = 0; ks < 6; ++ks) {
                bf8 Af = *(const bf8*)(sX + ((mi * 6 + ks) * 64 + l) * 8);
                a0 = __builtin_amdgcn_mfma_f32_16x16x32_bf16(Af, B0[ks], a0, 0, 0, 0);
                a1 = __builtin_amdgcn_mfma_f32_16x16x32_bf16(Af, B1[ks], a1, 0, 0, 0);
            }
            #pragma unroll
            for (int q = 0; q < 4; ++q) {
                int m = mi * 16 + lk * 4 + q;
                unsigned pv = (unsigned)f2b(fmaxf(a0[q] + bias0, 0.f))
                            | ((unsigned)f2b(fmaxf(a1[q] + bias1, 0.f)) << 16);
                *(unsigned*)(myHid + m * HIDP + 2 * lr) = pv;   // local k-cols 2lr, 2lr+1
            }
        }
        // GEMM2 on the wave's 32-k strip (permuted k matches W2f prep); wave-private LDS, in-order
        bf8 Wf2[6];
        const size_t w2base = ((size_t)w * 57 + u) * 6;
        #pragma unroll
        for (int nj = 0; nj < 6; ++nj)
            Wf2[nj] = *(const bf8*)(W2f + ((w2base + nj) * 64 + l) * 8);
        bf8 aF[4];
        #pragma unroll
        for (int mi = 0; mi < 4; ++mi)
            aF[mi] = *(const bf8*)(myHid + (mi * 16 + lr) * HIDP + lk * 8);
        #pragma unroll
        for (int nj = 0; nj < 6; ++nj)
            #pragma unroll
            for (int mi = 0; mi < 4; ++mi)
                acc2[mi][nj] = __builtin_amdgcn_mfma_f32_16x16x32_bf16(aF[mi], Wf2[nj], acc2[mi][nj], 0, 0, 0);
    }

    // cross-wave K-strip reduction (sX/sHid no longer needed -> alias)
    float* red1 = (float*)sX;
    float* red2 = (float*)&sHid[0][0];
    __syncthreads();
    if (w == 1 || w == 3) {
        float* r_ = (w == 1) ? red1 : red2;
        #pragma unroll
        for (int mi = 0; mi < 4; ++mi)
            #pragma unroll
            for (int nj = 0; nj < 6; ++nj)
                #pragma unroll
                for (int q = 0; q < 4; ++q)
                    r_[(mi * 16 + lk * 4 + q) * 96 + nj * 16 + lr] = acc2[mi][nj][q];
    }
    __syncthreads();
    if (w == 0 || w == 2) {
        float* r_ = (w == 0) ? red1 : red2;
        #pragma unroll
        for (int mi = 0; mi < 4; ++mi)
            #pragma unroll
            for (int nj = 0; nj < 6; ++nj)
                #pragma unroll
                for (int q = 0; q < 4; ++q)
                    r_[(mi * 16 + lk * 4 + q) * 96 + nj * 16 + lr] += acc2[mi][nj][q];
    }
    __syncthreads();
    float* dst = partial + ((size_t)split * B + m0) * 96;
    for (int i = tid; i < 64 * 96; i += 256) dst[i] = red1[i] + red2[i];
}

// ---------------- fused tail: combine 4 partials + FC3 + FC4 via MFMA ----------------
__global__ __launch_bounds__(256) void tail_mfma(
    const float* __restrict__ partial, const float* __restrict__ b2,
    const ushort* __restrict__ Xb,
    const ushort* __restrict__ wbf, const float* __restrict__ fc3_b,
    const float* __restrict__ fc4_b,
    float* __restrict__ o_kg, float* __restrict__ o_hSn, int B) {
    __shared__ __align__(16) ushort s3[16 * 200];
    __shared__ __align__(16) ushort s4[16 * 232];
    const int tid = threadIdx.x;
    const int w = tid >> 6, l = tid & 63, lr = l & 15, lk = l >> 4;
    const int row0 = blockIdx.x * 16;

    for (int i = tid; i < 16 * 200; i += 256) s3[i] = 0;
    for (int i = tid; i < 16 * 232; i += 256) s4[i] = 0;
    __syncthreads();
    for (int i = tid; i < 16 * 81; i += 256) {
        int r = i / 81, n = i - r * 81;
        s3[r * 200 + n] = Xb[(size_t)(row0 + r) * 192 + 100 + n];
    }
    for (int i = tid; i < 16 * 100; i += 256) {
        int r = i / 100, n = i - r * 100;
        s4[r * 232 + n] = Xb[(size_t)(row0 + r) * 192 + n];
    }
    for (int i = tid; i < 16 * 90; i += 256) {
        int r = i / 90, n = i - r * 90;
        size_t rw = (size_t)(row0 + r);
        float v = b2[n];
        #pragma unroll
        for (int s = 0; s < NSPLIT; ++s) v += partial[((size_t)s * B + rw) * 96 + n];
        o_kg[rw * 90 + n] = v;
        s3[r * 200 + 81 + n] = f2b(v);
    }
    __syncthreads();
    mfma_layer<6, 1>(s3, 200, wbf + WFC3O, 192, 7, fc3_b, 100, w, lr, lk,
                     nullptr, 0, s4, 232, 100, nullptr, 0, 0);
    __syncthreads();
    mfma_layer<7, 2>(s4, 232, wbf + WFC4O, 224, 7, fc4_b, 100, w, lr, lk,
                     nullptr, 0, nullptr, 0, 0, o_hSn, 100, row0);
}

extern "C" void kernel_launch(void* const* d_in, const int* in_sizes, int n_in,
                              void* d_out, int out_size, void* d_ws, size_t ws_size,
                              hipStream_t stream) {
    const float* obs_diff  = (const float*)d_in[0];
    const float* obs_innov = (const float*)d_in[1];
    const float* fw_evol   = (const float*)d_in[2];
    const float* fw_upd    = (const float*)d_in[3];
    const float* Q_Wih  = (const float*)d_in[4];
    const float* Q_Whh  = (const float*)d_in[5];
    const float* Q_bih  = (const float*)d_in[6];
    const float* Q_bhh  = (const float*)d_in[7];
    const float* Sig_Wih = (const float*)d_in[8];
    const float* Sig_bih = (const float*)d_in[10];
    const float* Sig_bhh = (const float*)d_in[11];
    const float* S_Wih  = (const float*)d_in[12];
    const float* S_Whh  = (const float*)d_in[13];
    const float* S_bih  = (const float*)d_in[14];
    const float* S_bhh  = (const float*)d_in[15];
    const float* R_Wih  = (const float*)d_in[16];
    const float* R_Whh  = (const float*)d_in[17];
    const float* R_bih  = (const float*)d_in[18];
    const float* R_bhh  = (const float*)d_in[19];
    const float* fc1_W = (const float*)d_in[20];
    const float* fc1_b = (const float*)d_in[21];
    const float* fc2_W1 = (const float*)d_in[22];
    const float* fc2_b1 = (const float*)d_in[23];
    const float* fc2_W2 = (const float*)d_in[24];
    const float* fc2_b2 = (const float*)d_in[25];
    const float* fc3_W = (const float*)d_in[26];
    const float* fc3_b = (const float*)d_in[27];
    const float* fc4_W = (const float*)d_in[28];
    const float* fc4_b = (const float*)d_in[29];
    const float* fc5_W = (const float*)d_in[30];
    const float* fc5_b = (const float*)d_in[31];
    const float* fc6_W = (const float*)d_in[32];
    const float* fc6_b = (const float*)d_in[33];
    const float* fc7_W = (const float*)d_in[34];
    const float* fc7_b = (const float*)d_in[35];
    const float* fc8_W = (const float*)d_in[36];
    const float* fc8_b = (const float*)d_in[37];

    const int B = in_sizes[0] / MD;   // 8192
    float* ws = (float*)d_ws;
    float* gh = ws;
    size_t off = 1024;
    ushort* wbf = (ushort*)(ws + off); off += WBF_TOTAL / 2;
    ushort* Xb  = (ushort*)(ws + off); off += (size_t)B * 96;      // [B][192] bf16
    ushort* Xf  = (ushort*)(ws + off); off += (size_t)B * 96;      // fragment-major X
    ushort* W1f = (ushort*)(ws + off); off += 456 * 6 * 64 * 8 / 2;
    ushort* W2f = (ushort*)(ws + off); off += 4 * 57 * 6 * 64 * 8 / 2;
    float* part = ws + off; off += (size_t)NSPLIT * B * 96;

    float* out = (float*)d_out;
    float* o_kg  = out;
    float* o_hS  = out + (size_t)B * 90;
    float* o_hSn = out + (size_t)B * 171;
    float* o_hQ  = out + (size_t)B * 271;
    float* o_hR  = out + (size_t)B * 371;

    hipLaunchKernelGGL(prep_all, dim3(NB_WBF + NB_W1F + NB_W2F + 1), dim3(256), 0, stream,
                       fc5_W, fc6_W, fc7_W, fc8_W, Q_Wih, Sig_Wih, R_Wih, S_Wih,
                       fc1_W, fc3_W, fc4_W, wbf,
                       fc2_W1, W1f, fc2_W2, W2f,
                       Q_Whh, Q_bhh, R_Whh, R_bhh, S_Whh, S_bhh, gh);
    hipLaunchKernelGGL(chain_mfma, dim3(B / 16), dim3(256), 0, stream,
                       obs_diff, obs_innov, fw_evol, fw_upd,
                       wbf, gh, Q_bih, Sig_bih, Sig_bhh, R_bih, S_bih,
                       fc1_b, fc5_b, fc6_b, fc7_b, fc8_b,
                       o_hQ, o_hR, o_hS, Xb, Xf);
    hipLaunchKernelGGL(fc2_mfma, dim3(128 * NSPLIT), dim3(256), 0, stream,
                       Xf, W1f, fc2_b1, W2f, part, B);
    hipLaunchKernelGGL(tail_mfma, dim3(B / 16), dim3(256), 0, stream,
                       part, fc2_b2, Xb, wbf, fc3_b, fc4_b,
                       o_kg, o_hSn, B);
}